// Round 7
// baseline (1144.135 us; speedup 1.0000x reference)
//
#include <hip/hip_runtime.h>
#include <hip/hip_bf16.h>

#define N_NODESC 100000
#define N_EDGESC 1600000
#define N_GRAPHSC 200
#define IN_DIMC 25
#define HIDC 256
#define OUT_DIMC 128
#define SCAN_BLK 1024
#define SCAN_NBLK ((N_NODESC + SCAN_BLK - 1) / SCAN_BLK)

typedef __attribute__((ext_vector_type(8))) short bf16x8;
typedef __attribute__((ext_vector_type(4))) float f32x4;

// ---------- bf16 helpers (raw ushort storage) ----------
__device__ inline float bf2f(unsigned short u) {
    union { float f; unsigned u32; } c;
    c.u32 = ((unsigned)u) << 16;
    return c.f;
}
__device__ inline unsigned short f2bf(float f) {
    union { float f; unsigned u; } c;
    c.f = f;
    unsigned r = (c.u + 0x7FFFu + ((c.u >> 16) & 1u)) >> 16;  // RNE
    return (unsigned short)r;
}
__device__ inline float u2f(unsigned u) {
    union { unsigned u; float f; } c;
    c.u = u;
    return c.f;
}

// ---------- utility fills ----------
__global__ void fill_u32(unsigned* __restrict__ p, unsigned v, int n) {
    int i = blockIdx.x * 256 + threadIdx.x;
    if (i < n) p[i] = v;
}

// ---------- degree / inv ----------
__global__ void deg_kernel(const int* __restrict__ dst, int* __restrict__ cnt, int E) {
    int i = blockIdx.x * 256 + threadIdx.x;
    if (i < E) atomicAdd(&cnt[dst[i]], 1);
}
__global__ void inv_kernel(const int* __restrict__ cnt, float* __restrict__ inv, int n) {
    int i = blockIdx.x * 256 + threadIdx.x;
    if (i < n) inv[i] = 1.0f / (float)max(cnt[i], 1);
}

// ---------- hierarchical exclusive scan over cnt[N] -> ofs[N+1] ----------
__global__ __launch_bounds__(SCAN_BLK) void scan_partial(const int* __restrict__ cnt,
                                                         int* __restrict__ ofs,
                                                         int* __restrict__ bsum) {
    __shared__ int sm[SCAN_BLK];
    int i = blockIdx.x * SCAN_BLK + threadIdx.x;
    int v = (i < N_NODESC) ? cnt[i] : 0;
    sm[threadIdx.x] = v;
    __syncthreads();
    for (int off = 1; off < SCAN_BLK; off <<= 1) {
        int t = (threadIdx.x >= off) ? sm[threadIdx.x - off] : 0;
        __syncthreads();
        sm[threadIdx.x] += t;
        __syncthreads();
    }
    if (i < N_NODESC) ofs[i] = sm[threadIdx.x] - v;  // exclusive within block
    if (threadIdx.x == SCAN_BLK - 1) bsum[blockIdx.x] = sm[SCAN_BLK - 1];
}

__global__ __launch_bounds__(128) void scan_bsums(int* __restrict__ bsum) {
    __shared__ int sm[SCAN_NBLK];
    if (threadIdx.x == 0) {
        int run = 0;
        for (int b = 0; b < SCAN_NBLK; ++b) {
            int t = bsum[b];
            sm[b] = run;
            run += t;
        }
        for (int b = 0; b < SCAN_NBLK; ++b) bsum[b] = sm[b];
    }
}

__global__ __launch_bounds__(SCAN_BLK) void scan_add(int* __restrict__ ofs,
                                                     const int* __restrict__ bsum) {
    int i = blockIdx.x * SCAN_BLK + threadIdx.x;
    if (i < N_NODESC) ofs[i] += bsum[blockIdx.x];
    if (i == 0) ofs[N_NODESC] = N_EDGESC;
}

// ---------- CSR fill ----------
__global__ void csr_fill(const int* __restrict__ src, const int* __restrict__ dst,
                         const int* __restrict__ ofs, int* __restrict__ cursor,
                         int* __restrict__ csr, int E) {
    int e = blockIdx.x * 256 + threadIdx.x;
    if (e < E) {
        int d = dst[e];
        int pos = atomicAdd(&cursor[d], 1);
        csr[ofs[d] + pos] = src[e];
    }
}

// ---------- graph ranges: boundary scan (batch sorted; no atomics) ----------
__global__ void ranges_bounds(const int* __restrict__ batch, int* __restrict__ gstart,
                              int* __restrict__ gend, int n) {
    int i = blockIdx.x * 256 + threadIdx.x;
    if (i >= n) return;
    int g = batch[i];
    if (i == 0 || batch[i - 1] != g) gstart[g] = i;
    if (i == n - 1 || batch[i + 1] != g) gend[g] = i + 1;
}

// ---------- weight transpose f32[256][256] -> bf16 WT[n][k] ----------
__global__ void wtransT(const float* __restrict__ W, unsigned short* __restrict__ WT) {
    __shared__ float t[16][17];
    int bx = blockIdx.x, by = blockIdx.y;
    int tx = threadIdx.x & 15, ty = threadIdx.x >> 4;
    t[ty][tx] = W[(by * 16 + ty) * HIDC + bx * 16 + tx];
    __syncthreads();
    WT[(size_t)(bx * 16 + ty) * HIDC + by * 16 + tx] = f2bf(t[tx][ty]);
}

// ---------- layer-1 mean gather (f32, 25 channels) ----------
__global__ void gather25(const float* __restrict__ x, const int* __restrict__ ofs,
                         const int* __restrict__ csr, const float* __restrict__ inv,
                         float* __restrict__ agg) {
    int idx = blockIdx.x * 256 + threadIdx.x;
    int node = idx >> 5, c = idx & 31;
    if (node >= N_NODESC || c >= IN_DIMC) return;
    float acc = 0.0f;
    int s = ofs[node], e = ofs[node + 1];
    for (int j = s; j < e; ++j) acc += x[(size_t)csr[j] * IN_DIMC + c];
    agg[(size_t)node * IN_DIMC + c] = acc * inv[node];
}

// ---------- hidden mean gather: one wave/node, half-wave/edge, 16B lanes ----------
__global__ void gather256(const unsigned short* __restrict__ h, const int* __restrict__ ofs,
                          const int* __restrict__ csr, const float* __restrict__ inv,
                          unsigned short* __restrict__ agg) {
    long long gtid = (long long)blockIdx.x * 256 + threadIdx.x;
    int node = (int)(gtid >> 6);
    if (node >= N_NODESC) return;
    const int lane = threadIdx.x & 63;
    const int half = lane >> 5;
    const int l = lane & 31;
    const int s = ofs[node], e = ofs[node + 1];

    float a0 = 0, a1 = 0, a2 = 0, a3 = 0, a4 = 0, a5 = 0, a6 = 0, a7 = 0;
    const size_t coff = (size_t)l * 8;

    int j = s + half;
    for (; j + 2 < e; j += 4) {
        int sn0 = csr[j];
        int sn1 = csr[j + 2];
        int4 v0 = *reinterpret_cast<const int4*>(h + (size_t)sn0 * HIDC + coff);
        int4 v1 = *reinterpret_cast<const int4*>(h + (size_t)sn1 * HIDC + coff);
        a0 += u2f(((unsigned)v0.x) << 16); a1 += u2f(((unsigned)v0.x) & 0xffff0000u);
        a2 += u2f(((unsigned)v0.y) << 16); a3 += u2f(((unsigned)v0.y) & 0xffff0000u);
        a4 += u2f(((unsigned)v0.z) << 16); a5 += u2f(((unsigned)v0.z) & 0xffff0000u);
        a6 += u2f(((unsigned)v0.w) << 16); a7 += u2f(((unsigned)v0.w) & 0xffff0000u);
        a0 += u2f(((unsigned)v1.x) << 16); a1 += u2f(((unsigned)v1.x) & 0xffff0000u);
        a2 += u2f(((unsigned)v1.y) << 16); a3 += u2f(((unsigned)v1.y) & 0xffff0000u);
        a4 += u2f(((unsigned)v1.z) << 16); a5 += u2f(((unsigned)v1.z) & 0xffff0000u);
        a6 += u2f(((unsigned)v1.w) << 16); a7 += u2f(((unsigned)v1.w) & 0xffff0000u);
    }
    if (j < e) {
        int sn0 = csr[j];
        int4 v0 = *reinterpret_cast<const int4*>(h + (size_t)sn0 * HIDC + coff);
        a0 += u2f(((unsigned)v0.x) << 16); a1 += u2f(((unsigned)v0.x) & 0xffff0000u);
        a2 += u2f(((unsigned)v0.y) << 16); a3 += u2f(((unsigned)v0.y) & 0xffff0000u);
        a4 += u2f(((unsigned)v0.z) << 16); a5 += u2f(((unsigned)v0.z) & 0xffff0000u);
        a6 += u2f(((unsigned)v0.w) << 16); a7 += u2f(((unsigned)v0.w) & 0xffff0000u);
    }

    a0 += __shfl_xor(a0, 32, 64); a1 += __shfl_xor(a1, 32, 64);
    a2 += __shfl_xor(a2, 32, 64); a3 += __shfl_xor(a3, 32, 64);
    a4 += __shfl_xor(a4, 32, 64); a5 += __shfl_xor(a5, 32, 64);
    a6 += __shfl_xor(a6, 32, 64); a7 += __shfl_xor(a7, 32, 64);

    if (half == 0) {
        float sc = inv[node];
        int4 p;
        p.x = (int)((unsigned)f2bf(a0 * sc) | ((unsigned)f2bf(a1 * sc) << 16));
        p.y = (int)((unsigned)f2bf(a2 * sc) | ((unsigned)f2bf(a3 * sc) << 16));
        p.z = (int)((unsigned)f2bf(a4 * sc) | ((unsigned)f2bf(a5 * sc) << 16));
        p.w = (int)((unsigned)f2bf(a6 * sc) | ((unsigned)f2bf(a7 * sc) << 16));
        *reinterpret_cast<int4*>(agg + (size_t)node * HIDC + coff) = p;
    }
}

// ---------- layer-1 f32 SAGE GEMM (K=25) ----------
template <int K>
__global__ __launch_bounds__(256) void sage_gemm_f32(
    const float* __restrict__ agg, const float* __restrict__ h,
    const float* __restrict__ Wl, const float* __restrict__ Wr,
    const float* __restrict__ bias,
    unsigned short* __restrict__ out, int nrows) {
    constexpr int BM = 64, BN = 64, BK = 16;
    __shared__ float sA[BK][BM + 4];
    __shared__ float sB[BK][BN + 4];
    const int tid = threadIdx.x;
    const int tx = tid & 15, ty = tid >> 4;
    const int rowbase = blockIdx.x * BM;
    const int colbase = blockIdx.y * BN;
    float acc[4][4] = {};
    const int lrow = tid >> 2, lkq = (tid & 3) * 4;
    const int lkB = tid >> 4, lnB = (tid & 15) * 4;

    for (int pass = 0; pass < 2; ++pass) {
        const float* __restrict__ A = pass ? h : agg;
        const float* __restrict__ W = pass ? Wr : Wl;
        const int grow = rowbase + lrow;
        for (int kb = 0; kb < K; kb += BK) {
#pragma unroll
            for (int j = 0; j < 4; ++j) {
                int k = kb + lkq + j;
                float v = 0.0f;
                if (grow < nrows && k < K) v = A[(size_t)grow * K + k];
                sA[lkq + j][lrow] = v;
            }
#pragma unroll
            for (int j = 0; j < 4; ++j) {
                int k = kb + lkB;
                int n = colbase + lnB + j;
                sB[lkB][lnB + j] = (k < K) ? W[(size_t)k * HIDC + n] : 0.0f;
            }
            __syncthreads();
#pragma unroll
            for (int kk = 0; kk < BK; ++kk) {
                float a[4], b[4];
#pragma unroll
                for (int i = 0; i < 4; ++i) a[i] = sA[kk][ty * 4 + i];
#pragma unroll
                for (int j = 0; j < 4; ++j) b[j] = sB[kk][tx * 4 + j];
#pragma unroll
                for (int i = 0; i < 4; ++i)
#pragma unroll
                    for (int j = 0; j < 4; ++j) acc[i][j] += a[i] * b[j];
            }
            __syncthreads();
        }
    }
#pragma unroll
    for (int i = 0; i < 4; ++i) {
        int r = rowbase + ty * 4 + i;
        if (r >= nrows) continue;
#pragma unroll
        for (int j = 0; j < 4; ++j) {
            int c = colbase + tx * 4 + j;
            out[(size_t)r * HIDC + c] = f2bf(fmaxf(acc[i][j] + bias[c], 0.0f));
        }
    }
}

// ---------- MFMA bf16 SAGE GEMM, LDS-free direct-register version ----------
// out = relu(A0@B0 + A1@B1 + b). A: [M][256] bf16. BnT: [256 n][256 k] bf16.
// One block = 128 rows x 256 cols. 8 waves (2x4); wave tile 64x64 = 4x4 frags.
// A frags: 16 x 64B coalesced segments, streamed once from HBM.
// B frags: L2-resident (reused by all blocks). No LDS, no barriers.
__global__ __launch_bounds__(512) void sage_gemm_mfma(
    const unsigned short* __restrict__ A0, const unsigned short* __restrict__ A1,
    const unsigned short* __restrict__ B0T, const unsigned short* __restrict__ B1T,
    const float* __restrict__ bias, unsigned short* __restrict__ out, int M) {
    constexpr int KD = 256;
    const int tid = threadIdx.x;
    const int lane = tid & 63;
    const int wid = tid >> 6;      // 0..7
    const int wm = wid >> 2;       // 0..1  (row half)
    const int wn = wid & 3;        // 0..3  (col quarter)
    const int rowbase = blockIdx.x * 128;
    const int fr = lane & 15;
    const int kq8 = (lane >> 4) << 3;  // 0,8,16,24

    f32x4 acc[4][4] = {};
    const int arow0 = rowbase + wm * 64 + fr;
    const int brow0 = wn * 64 + fr;

    for (int pass = 0; pass < 2; ++pass) {
        const unsigned short* __restrict__ A = pass ? A1 : A0;
        const unsigned short* __restrict__ BT = pass ? B1T : B0T;
        int4 a_c[4], b_c[4], a_n[4], b_n[4];
#pragma unroll
        for (int i = 0; i < 4; ++i) {
            int r = arow0 + i * 16;
            a_c[i] = (r < M) ? *reinterpret_cast<const int4*>(A + (size_t)r * KD + kq8)
                             : make_int4(0, 0, 0, 0);
            b_c[i] = *reinterpret_cast<const int4*>(BT + (size_t)(brow0 + i * 16) * KD + kq8);
        }
        for (int kb = 0; kb < 7; ++kb) {
            const int ko = (kb + 1) * 32 + kq8;
#pragma unroll
            for (int i = 0; i < 4; ++i) {
                int r = arow0 + i * 16;
                a_n[i] = (r < M) ? *reinterpret_cast<const int4*>(A + (size_t)r * KD + ko)
                                 : make_int4(0, 0, 0, 0);
                b_n[i] = *reinterpret_cast<const int4*>(BT + (size_t)(brow0 + i * 16) * KD + ko);
            }
#pragma unroll
            for (int i = 0; i < 4; ++i)
#pragma unroll
                for (int j = 0; j < 4; ++j)
                    acc[i][j] = __builtin_amdgcn_mfma_f32_16x16x32_bf16(
                        __builtin_bit_cast(bf16x8, a_c[i]), __builtin_bit_cast(bf16x8, b_c[j]),
                        acc[i][j], 0, 0, 0);
#pragma unroll
            for (int i = 0; i < 4; ++i) { a_c[i] = a_n[i]; b_c[i] = b_n[i]; }
        }
#pragma unroll
        for (int i = 0; i < 4; ++i)
#pragma unroll
            for (int j = 0; j < 4; ++j)
                acc[i][j] = __builtin_amdgcn_mfma_f32_16x16x32_bf16(
                    __builtin_bit_cast(bf16x8, a_c[i]), __builtin_bit_cast(bf16x8, b_c[j]),
                    acc[i][j], 0, 0, 0);
    }

    // epilogue: C/D layout col=lane&15, row=4*(lane>>4)+r
    const int crow0 = (lane >> 4) << 2;
#pragma unroll
    for (int i = 0; i < 4; ++i) {
#pragma unroll
        for (int j = 0; j < 4; ++j) {
            int col = wn * 64 + j * 16 + fr;
            float bb = bias[col];
#pragma unroll
            for (int r = 0; r < 4; ++r) {
                int row = rowbase + wm * 64 + i * 16 + crow0 + r;
                if (row < M)
                    out[(size_t)row * HIDC + col] = f2bf(fmaxf(acc[i][j][r] + bb, 0.0f));
            }
        }
    }
}

// ---------- segment-max pool ----------
__global__ void pool_max(const unsigned short* __restrict__ h, const int* __restrict__ gstart,
                         const int* __restrict__ gend, float* __restrict__ xc, int col_off) {
    int g = blockIdx.x;
    int c = threadIdx.x;
    float m = 0.0f;
    int s = gstart[g], e = gend[g];
    for (int i = s; i < e; ++i) m = fmaxf(m, bf2f(h[(size_t)i * HIDC + c]));
    xc[(size_t)g * (3 * HIDC) + col_off + c] = m;
}

// ---------- head MLPs ----------
__global__ void mlp1(const float* __restrict__ xc, const float* __restrict__ W,
                     const float* __restrict__ b, float* __restrict__ hmid) {
    __shared__ float row[3 * HIDC];
    int g = blockIdx.x;
    for (int i = threadIdx.x; i < 3 * HIDC; i += 256) row[i] = xc[(size_t)g * (3 * HIDC) + i];
    __syncthreads();
    float acc = b[threadIdx.x];
    for (int k = 0; k < 3 * HIDC; ++k) acc += row[k] * W[(size_t)k * HIDC + threadIdx.x];
    hmid[(size_t)g * HIDC + threadIdx.x] = fmaxf(acc, 0.0f);
}

__global__ void mlp2(const float* __restrict__ hmid, const float* __restrict__ W,
                     const float* __restrict__ b, float* __restrict__ out) {
    __shared__ float row[HIDC];
    int g = blockIdx.x;
    for (int i = threadIdx.x; i < HIDC; i += 128) row[i] = hmid[(size_t)g * HIDC + i];
    __syncthreads();
    float acc = b[threadIdx.x];
    for (int k = 0; k < HIDC; ++k) acc += row[k] * W[(size_t)k * OUT_DIMC + threadIdx.x];
    out[(size_t)g * OUT_DIMC + threadIdx.x] = acc;
}

static inline char* align_up(char* p, size_t a) {
    return (char*)(((uintptr_t)p + a - 1) & ~(uintptr_t)(a - 1));
}

extern "C" void kernel_launch(void* const* d_in, const int* in_sizes, int n_in,
                              void* d_out, int out_size, void* d_ws, size_t ws_size,
                              hipStream_t stream) {
    const float* x = (const float*)d_in[0];
    const int* edge_index = (const int*)d_in[1];
    const int* batch = (const int*)d_in[2];
    const float* W1l = (const float*)d_in[3];
    const float* W1r = (const float*)d_in[4];
    const float* b1 = (const float*)d_in[5];
    const float* W2l = (const float*)d_in[6];
    const float* W2r = (const float*)d_in[7];
    const float* b2 = (const float*)d_in[8];
    const float* W3l = (const float*)d_in[9];
    const float* W3r = (const float*)d_in[10];
    const float* b3 = (const float*)d_in[11];
    const float* Wlin1 = (const float*)d_in[12];
    const float* blin1 = (const float*)d_in[13];
    const float* Wlin2 = (const float*)d_in[14];
    const float* blin2 = (const float*)d_in[15];
    float* out = (float*)d_out;

    const int N = N_NODESC, E = N_EDGESC;
    const int* src = edge_index;
    const int* dst = edge_index + E;

    // ---- workspace carve-up ----
    char* w0 = (char*)d_ws;
    char* w = w0;
    int* cnt = (int*)w;        w = align_up(w + (size_t)N * 4, 256);
    float* invc = (float*)w;   w = align_up(w + (size_t)N * 4, 256);
    int* row_ofs = (int*)w;    w = align_up(w + (size_t)(N + 1) * 4, 256);
    int* bsum = (int*)w;       w = align_up(w + (size_t)SCAN_NBLK * 4, 256);
    int* csr = (int*)w;        w = align_up(w + (size_t)E * 4, 256);
    int* gstart = (int*)w;     w = align_up(w + (size_t)N_GRAPHSC * 4, 256);
    int* gend = (int*)w;       w = align_up(w + (size_t)N_GRAPHSC * 4, 256);
    float* xc = (float*)w;     w = align_up(w + (size_t)N_GRAPHSC * 3 * HIDC * 4, 256);
    float* hmid = (float*)w;   w = align_up(w + (size_t)N_GRAPHSC * HIDC * 4, 256);
    unsigned short* W2lT = (unsigned short*)w; w = align_up(w + (size_t)HIDC * HIDC * 2, 256);
    unsigned short* W2rT = (unsigned short*)w; w = align_up(w + (size_t)HIDC * HIDC * 2, 256);
    unsigned short* W3lT = (unsigned short*)w; w = align_up(w + (size_t)HIDC * HIDC * 2, 256);
    unsigned short* W3rT = (unsigned short*)w; w = align_up(w + (size_t)HIDC * HIDC * 2, 256);
    char* aggU = w;            w = align_up(w + (size_t)N * HIDC * 2, 256);
    unsigned short* h1 = (unsigned short*)w;  w = align_up(w + (size_t)N * HIDC * 2, 256);
    unsigned short* h2 = (unsigned short*)w;  w = align_up(w + (size_t)N * HIDC * 2, 256);
    size_t required = (size_t)(w - w0);
    if (ws_size < required) return;

    float* agg25 = (float*)aggU;
    unsigned short* aggH = (unsigned short*)aggU;

    const int nbN = (N + 255) / 256;
    const int nbE = (E + 255) / 256;
    const dim3 gemm_grid_f32((N + 63) / 64, HIDC / 64);
    const int gemm_grid_mfma = (N + 127) / 128;
    const dim3 tgrid(16, 16);

    // weight transposes
    wtransT<<<tgrid, 256, 0, stream>>>(W2l, W2lT);
    wtransT<<<tgrid, 256, 0, stream>>>(W2r, W2rT);
    wtransT<<<tgrid, 256, 0, stream>>>(W3l, W3lT);
    wtransT<<<tgrid, 256, 0, stream>>>(W3r, W3rT);

    // degrees + inv
    fill_u32<<<nbN, 256, 0, stream>>>((unsigned*)cnt, 0u, N);
    deg_kernel<<<nbE, 256, 0, stream>>>(dst, cnt, E);
    inv_kernel<<<nbN, 256, 0, stream>>>(cnt, invc, N);
    // CSR offsets: hierarchical scan
    scan_partial<<<SCAN_NBLK, SCAN_BLK, 0, stream>>>(cnt, row_ofs, bsum);
    scan_bsums<<<1, 128, 0, stream>>>(bsum);
    scan_add<<<SCAN_NBLK, SCAN_BLK, 0, stream>>>(row_ofs, bsum);
    fill_u32<<<nbN, 256, 0, stream>>>((unsigned*)cnt, 0u, N);
    csr_fill<<<nbE, 256, 0, stream>>>(src, dst, row_ofs, cnt, csr, E);
    // graph ranges
    fill_u32<<<1, 256, 0, stream>>>((unsigned*)gstart, (unsigned)N, N_GRAPHSC);
    fill_u32<<<1, 256, 0, stream>>>((unsigned*)gend, 0u, N_GRAPHSC);
    ranges_bounds<<<nbN, 256, 0, stream>>>(batch, gstart, gend, N);

    // ---- layer 1 (K=25, f32) ----
    gather25<<<(N * 32 + 255) / 256, 256, 0, stream>>>(x, row_ofs, csr, invc, agg25);
    sage_gemm_f32<IN_DIMC><<<gemm_grid_f32, 256, 0, stream>>>(agg25, x, W1l, W1r, b1, h1, N);
    pool_max<<<N_GRAPHSC, 256, 0, stream>>>(h1, gstart, gend, xc, 0);

    // ---- layer 2 (MFMA, LDS-free) ----
    gather256<<<(N * 64 + 255) / 256, 256, 0, stream>>>(h1, row_ofs, csr, invc, aggH);
    sage_gemm_mfma<<<gemm_grid_mfma, 512, 0, stream>>>(aggH, h1, W2lT, W2rT, b2, h2, N);
    pool_max<<<N_GRAPHSC, 256, 0, stream>>>(h2, gstart, gend, xc, HIDC);

    // ---- layer 3 (MFMA, LDS-free) ----
    gather256<<<(N * 64 + 255) / 256, 256, 0, stream>>>(h2, row_ofs, csr, invc, aggH);
    sage_gemm_mfma<<<gemm_grid_mfma, 512, 0, stream>>>(aggH, h2, W3lT, W3rT, b3, h1, N);
    pool_max<<<N_GRAPHSC, 256, 0, stream>>>(h1, gstart, gend, xc, 2 * HIDC);

    // ---- head ----
    mlp1<<<N_GRAPHSC, 256, 0, stream>>>(xc, Wlin1, blin1, hmid);
    mlp2<<<N_GRAPHSC, 128, 0, stream>>>(hmid, Wlin2, blin2, out);
}

// Round 8
// 1128.794 us; speedup vs baseline: 1.0136x; 1.0136x over previous
//
#include <hip/hip_runtime.h>
#include <hip/hip_bf16.h>

#define N_NODESC 100000
#define N_EDGESC 1600000
#define N_GRAPHSC 200
#define IN_DIMC 25
#define HIDC 256
#define OUT_DIMC 128
#define SCAN_BLK 1024
#define SCAN_NBLK ((N_NODESC + SCAN_BLK - 1) / SCAN_BLK)
#define NRB ((N_NODESC + 127) / 128)            // 782 row-blocks
#define GEMM_GRID ((((NRB) + 7) / 8) * 16)      // 98 groups x 16 = 1568

typedef __attribute__((ext_vector_type(8))) short bf16x8;
typedef __attribute__((ext_vector_type(4))) float f32x4;

// ---------- bf16 helpers (raw ushort storage) ----------
__device__ inline float bf2f(unsigned short u) {
    union { float f; unsigned u32; } c;
    c.u32 = ((unsigned)u) << 16;
    return c.f;
}
__device__ inline unsigned short f2bf(float f) {
    union { float f; unsigned u; } c;
    c.f = f;
    unsigned r = (c.u + 0x7FFFu + ((c.u >> 16) & 1u)) >> 16;  // RNE
    return (unsigned short)r;
}
__device__ inline float u2f(unsigned u) {
    union { unsigned u; float f; } c;
    c.u = u;
    return c.f;
}

// ---------- utility fills ----------
__global__ void fill_u32(unsigned* __restrict__ p, unsigned v, int n) {
    int i = blockIdx.x * 256 + threadIdx.x;
    if (i < n) p[i] = v;
}

// ---------- degree / inv ----------
__global__ void deg_kernel(const int* __restrict__ dst, int* __restrict__ cnt, int E) {
    int i = blockIdx.x * 256 + threadIdx.x;
    if (i < E) atomicAdd(&cnt[dst[i]], 1);
}
__global__ void inv_kernel(const int* __restrict__ cnt, float* __restrict__ inv, int n) {
    int i = blockIdx.x * 256 + threadIdx.x;
    if (i < n) inv[i] = 1.0f / (float)max(cnt[i], 1);
}

// ---------- hierarchical exclusive scan over cnt[N] -> ofs[N+1] ----------
__global__ __launch_bounds__(SCAN_BLK) void scan_partial(const int* __restrict__ cnt,
                                                         int* __restrict__ ofs,
                                                         int* __restrict__ bsum) {
    __shared__ int sm[SCAN_BLK];
    int i = blockIdx.x * SCAN_BLK + threadIdx.x;
    int v = (i < N_NODESC) ? cnt[i] : 0;
    sm[threadIdx.x] = v;
    __syncthreads();
    for (int off = 1; off < SCAN_BLK; off <<= 1) {
        int t = (threadIdx.x >= off) ? sm[threadIdx.x - off] : 0;
        __syncthreads();
        sm[threadIdx.x] += t;
        __syncthreads();
    }
    if (i < N_NODESC) ofs[i] = sm[threadIdx.x] - v;  // exclusive within block
    if (threadIdx.x == SCAN_BLK - 1) bsum[blockIdx.x] = sm[SCAN_BLK - 1];
}

__global__ __launch_bounds__(128) void scan_bsums(int* __restrict__ bsum) {
    __shared__ int sm[SCAN_NBLK];
    if (threadIdx.x == 0) {
        int run = 0;
        for (int b = 0; b < SCAN_NBLK; ++b) {
            int t = bsum[b];
            sm[b] = run;
            run += t;
        }
        for (int b = 0; b < SCAN_NBLK; ++b) bsum[b] = sm[b];
    }
}

__global__ __launch_bounds__(SCAN_BLK) void scan_add(int* __restrict__ ofs,
                                                     const int* __restrict__ bsum) {
    int i = blockIdx.x * SCAN_BLK + threadIdx.x;
    if (i < N_NODESC) ofs[i] += bsum[blockIdx.x];
    if (i == 0) ofs[N_NODESC] = N_EDGESC;
}

// ---------- CSR fill ----------
__global__ void csr_fill(const int* __restrict__ src, const int* __restrict__ dst,
                         const int* __restrict__ ofs, int* __restrict__ cursor,
                         int* __restrict__ csr, int E) {
    int e = blockIdx.x * 256 + threadIdx.x;
    if (e < E) {
        int d = dst[e];
        int pos = atomicAdd(&cursor[d], 1);
        csr[ofs[d] + pos] = src[e];
    }
}

// ---------- graph ranges: boundary scan (batch sorted; no atomics) ----------
__global__ void ranges_bounds(const int* __restrict__ batch, int* __restrict__ gstart,
                              int* __restrict__ gend, int n) {
    int i = blockIdx.x * 256 + threadIdx.x;
    if (i >= n) return;
    int g = batch[i];
    if (i == 0 || batch[i - 1] != g) gstart[g] = i;
    if (i == n - 1 || batch[i + 1] != g) gend[g] = i + 1;
}

// ---------- weight transpose f32[256][256] -> bf16 WT[n][k] ----------
__global__ void wtransT(const float* __restrict__ W, unsigned short* __restrict__ WT) {
    __shared__ float t[16][17];
    int bx = blockIdx.x, by = blockIdx.y;
    int tx = threadIdx.x & 15, ty = threadIdx.x >> 4;
    t[ty][tx] = W[(by * 16 + ty) * HIDC + bx * 16 + tx];
    __syncthreads();
    WT[(size_t)(bx * 16 + ty) * HIDC + by * 16 + tx] = f2bf(t[tx][ty]);
}

// ---------- layer-1 mean gather (f32, 25 channels) ----------
__global__ void gather25(const float* __restrict__ x, const int* __restrict__ ofs,
                         const int* __restrict__ csr, const float* __restrict__ inv,
                         float* __restrict__ agg) {
    int idx = blockIdx.x * 256 + threadIdx.x;
    int node = idx >> 5, c = idx & 31;
    if (node >= N_NODESC || c >= IN_DIMC) return;
    float acc = 0.0f;
    int s = ofs[node], e = ofs[node + 1];
    for (int j = s; j < e; ++j) acc += x[(size_t)csr[j] * IN_DIMC + c];
    agg[(size_t)node * IN_DIMC + c] = acc * inv[node];
}

// ---------- hidden mean gather: one wave/node, half-wave/edge, 16B lanes ----------
__global__ void gather256(const unsigned short* __restrict__ h, const int* __restrict__ ofs,
                          const int* __restrict__ csr, const float* __restrict__ inv,
                          unsigned short* __restrict__ agg) {
    long long gtid = (long long)blockIdx.x * 256 + threadIdx.x;
    int node = (int)(gtid >> 6);
    if (node >= N_NODESC) return;
    const int lane = threadIdx.x & 63;
    const int half = lane >> 5;
    const int l = lane & 31;
    const int s = ofs[node], e = ofs[node + 1];

    float a0 = 0, a1 = 0, a2 = 0, a3 = 0, a4 = 0, a5 = 0, a6 = 0, a7 = 0;
    const size_t coff = (size_t)l * 8;

    int j = s + half;
    for (; j + 2 < e; j += 4) {
        int sn0 = csr[j];
        int sn1 = csr[j + 2];
        int4 v0 = *reinterpret_cast<const int4*>(h + (size_t)sn0 * HIDC + coff);
        int4 v1 = *reinterpret_cast<const int4*>(h + (size_t)sn1 * HIDC + coff);
        a0 += u2f(((unsigned)v0.x) << 16); a1 += u2f(((unsigned)v0.x) & 0xffff0000u);
        a2 += u2f(((unsigned)v0.y) << 16); a3 += u2f(((unsigned)v0.y) & 0xffff0000u);
        a4 += u2f(((unsigned)v0.z) << 16); a5 += u2f(((unsigned)v0.z) & 0xffff0000u);
        a6 += u2f(((unsigned)v0.w) << 16); a7 += u2f(((unsigned)v0.w) & 0xffff0000u);
        a0 += u2f(((unsigned)v1.x) << 16); a1 += u2f(((unsigned)v1.x) & 0xffff0000u);
        a2 += u2f(((unsigned)v1.y) << 16); a3 += u2f(((unsigned)v1.y) & 0xffff0000u);
        a4 += u2f(((unsigned)v1.z) << 16); a5 += u2f(((unsigned)v1.z) & 0xffff0000u);
        a6 += u2f(((unsigned)v1.w) << 16); a7 += u2f(((unsigned)v1.w) & 0xffff0000u);
    }
    if (j < e) {
        int sn0 = csr[j];
        int4 v0 = *reinterpret_cast<const int4*>(h + (size_t)sn0 * HIDC + coff);
        a0 += u2f(((unsigned)v0.x) << 16); a1 += u2f(((unsigned)v0.x) & 0xffff0000u);
        a2 += u2f(((unsigned)v0.y) << 16); a3 += u2f(((unsigned)v0.y) & 0xffff0000u);
        a4 += u2f(((unsigned)v0.z) << 16); a5 += u2f(((unsigned)v0.z) & 0xffff0000u);
        a6 += u2f(((unsigned)v0.w) << 16); a7 += u2f(((unsigned)v0.w) & 0xffff0000u);
    }

    a0 += __shfl_xor(a0, 32, 64); a1 += __shfl_xor(a1, 32, 64);
    a2 += __shfl_xor(a2, 32, 64); a3 += __shfl_xor(a3, 32, 64);
    a4 += __shfl_xor(a4, 32, 64); a5 += __shfl_xor(a5, 32, 64);
    a6 += __shfl_xor(a6, 32, 64); a7 += __shfl_xor(a7, 32, 64);

    if (half == 0) {
        float sc = inv[node];
        int4 p;
        p.x = (int)((unsigned)f2bf(a0 * sc) | ((unsigned)f2bf(a1 * sc) << 16));
        p.y = (int)((unsigned)f2bf(a2 * sc) | ((unsigned)f2bf(a3 * sc) << 16));
        p.z = (int)((unsigned)f2bf(a4 * sc) | ((unsigned)f2bf(a5 * sc) << 16));
        p.w = (int)((unsigned)f2bf(a6 * sc) | ((unsigned)f2bf(a7 * sc) << 16));
        *reinterpret_cast<int4*>(agg + (size_t)node * HIDC + coff) = p;
    }
}

// ---------- layer-1 f32 SAGE GEMM (K=25) ----------
template <int K>
__global__ __launch_bounds__(256) void sage_gemm_f32(
    const float* __restrict__ agg, const float* __restrict__ h,
    const float* __restrict__ Wl, const float* __restrict__ Wr,
    const float* __restrict__ bias,
    unsigned short* __restrict__ out, int nrows) {
    constexpr int BM = 64, BN = 64, BK = 16;
    __shared__ float sA[BK][BM + 4];
    __shared__ float sB[BK][BN + 4];
    const int tid = threadIdx.x;
    const int tx = tid & 15, ty = tid >> 4;
    const int rowbase = blockIdx.x * BM;
    const int colbase = blockIdx.y * BN;
    float acc[4][4] = {};
    const int lrow = tid >> 2, lkq = (tid & 3) * 4;
    const int lkB = tid >> 4, lnB = (tid & 15) * 4;

    for (int pass = 0; pass < 2; ++pass) {
        const float* __restrict__ A = pass ? h : agg;
        const float* __restrict__ W = pass ? Wr : Wl;
        const int grow = rowbase + lrow;
        for (int kb = 0; kb < K; kb += BK) {
#pragma unroll
            for (int j = 0; j < 4; ++j) {
                int k = kb + lkq + j;
                float v = 0.0f;
                if (grow < nrows && k < K) v = A[(size_t)grow * K + k];
                sA[lkq + j][lrow] = v;
            }
#pragma unroll
            for (int j = 0; j < 4; ++j) {
                int k = kb + lkB;
                int n = colbase + lnB + j;
                sB[lkB][lnB + j] = (k < K) ? W[(size_t)k * HIDC + n] : 0.0f;
            }
            __syncthreads();
#pragma unroll
            for (int kk = 0; kk < BK; ++kk) {
                float a[4], b[4];
#pragma unroll
                for (int i = 0; i < 4; ++i) a[i] = sA[kk][ty * 4 + i];
#pragma unroll
                for (int j = 0; j < 4; ++j) b[j] = sB[kk][tx * 4 + j];
#pragma unroll
                for (int i = 0; i < 4; ++i)
#pragma unroll
                    for (int j = 0; j < 4; ++j) acc[i][j] += a[i] * b[j];
            }
            __syncthreads();
        }
    }
#pragma unroll
    for (int i = 0; i < 4; ++i) {
        int r = rowbase + ty * 4 + i;
        if (r >= nrows) continue;
#pragma unroll
        for (int j = 0; j < 4; ++j) {
            int c = colbase + tx * 4 + j;
            out[(size_t)r * HIDC + c] = f2bf(fmaxf(acc[i][j] + bias[c], 0.0f));
        }
    }
}

// ---------- MFMA bf16 SAGE GEMM: B-in-LDS (swizzled), barrier-free K loop ----------
// out = relu(A0@B0 + A1@B1 + b). A: [M][256] bf16. BnT: [256 n][256 k] bf16.
// 256 threads = 4 waves (2x2), tile 128 rows x 128 cols; per 128-k half: stage
// B slice [128 cols][128 k] into 32KB swizzled LDS (2 barriers), then 4 k-steps
// with ds_read B + 2-deep-prefetched global A, no barriers.
// Grid: groups of 16 bids = 8 rowblks x 2 colblks; bid and bid+8 share bid%8
// (same XCD) so the paired col-block's A re-read hits that XCD's L2.
__global__ __launch_bounds__(256) void sage_gemm_mfma(
    const unsigned short* __restrict__ A0, const unsigned short* __restrict__ A1,
    const unsigned short* __restrict__ B0T, const unsigned short* __restrict__ B1T,
    const float* __restrict__ bias, unsigned short* __restrict__ out, int M) {
    constexpr int KD = 256;
    __shared__ unsigned short sB[128 * 128];  // 32KB, [row][k-half] with XOR swizzle
    const int bid = blockIdx.x;
    const int rowblk = (bid >> 4) * 8 + (bid & 7);
    const int colblk = (bid >> 3) & 1;
    if (rowblk >= NRB) return;  // uniform per block: safe with barriers below
    const int rowbase = rowblk * 128, colbase = colblk * 128;
    const int tid = threadIdx.x;
    const int lane = tid & 63;
    const int wid = tid >> 6;
    const int wm = wid >> 1, wn = wid & 1;
    const int fr = lane & 15;
    const int kq8 = (lane >> 4) << 3;  // 0,8,16,24

    f32x4 acc[4][4] = {};
    const int arow0 = rowbase + wm * 64 + fr;

#pragma unroll
    for (int pass = 0; pass < 2; ++pass) {
        const unsigned short* __restrict__ A = pass ? A1 : A0;
        const unsigned short* __restrict__ BT = pass ? B1T : B0T;
#pragma unroll
        for (int half = 0; half < 2; ++half) {
            const int kbase = half * 128;
            // ---- stage B slice: [128 rows=cols of C][128 k] -> swizzled LDS ----
            int4 gv[8];
#pragma unroll
            for (int c = 0; c < 8; ++c) {
                int chunk = (c << 8) + tid;        // 2048 chunks of 16B
                int r = chunk >> 4, k16 = chunk & 15;
                gv[c] = *reinterpret_cast<const int4*>(
                    BT + (size_t)(colbase + r) * KD + kbase + k16 * 8);
            }
            __syncthreads();  // previous half's reads complete before overwrite
#pragma unroll
            for (int c = 0; c < 8; ++c) {
                int chunk = (c << 8) + tid;
                int r = chunk >> 4, k16 = chunk & 15;
                int byte = (r * 256 + k16 * 16) ^ ((r & 7) << 4);
                *reinterpret_cast<int4*>(reinterpret_cast<char*>(sB) + byte) = gv[c];
            }
            __syncthreads();
            // ---- 4 k-steps, no barriers; A prefetched 2 deep ----
            int4 ac[4], an[4];
#pragma unroll
            for (int i = 0; i < 4; ++i) {
                int r = arow0 + i * 16;
                ac[i] = (r < M) ? *reinterpret_cast<const int4*>(A + (size_t)r * KD + kbase + kq8)
                                : make_int4(0, 0, 0, 0);
                an[i] = (r < M) ? *reinterpret_cast<const int4*>(A + (size_t)r * KD + kbase + 32 + kq8)
                                : make_int4(0, 0, 0, 0);
            }
#pragma unroll
            for (int ks = 0; ks < 4; ++ks) {
                bf16x8 bfrag[4];
#pragma unroll
                for (int i = 0; i < 4; ++i) {
                    int row = wn * 64 + i * 16 + fr;
                    int byte = (row * 256 + ks * 64 + kq8 * 2) ^ ((row & 7) << 4);
                    bfrag[i] = *reinterpret_cast<const bf16x8*>(
                        reinterpret_cast<const char*>(sB) + byte);
                }
                int4 af[4];
                if (ks < 2) {
#pragma unroll
                    for (int i = 0; i < 4; ++i) {
                        int r = arow0 + i * 16;
                        af[i] = (r < M)
                                    ? *reinterpret_cast<const int4*>(
                                          A + (size_t)r * KD + kbase + (ks + 2) * 32 + kq8)
                                    : make_int4(0, 0, 0, 0);
                    }
                }
#pragma unroll
                for (int i = 0; i < 4; ++i)
#pragma unroll
                    for (int j = 0; j < 4; ++j)
                        acc[i][j] = __builtin_amdgcn_mfma_f32_16x16x32_bf16(
                            __builtin_bit_cast(bf16x8, ac[i]), bfrag[j], acc[i][j], 0, 0, 0);
#pragma unroll
                for (int i = 0; i < 4; ++i) { ac[i] = an[i]; an[i] = af[i]; }
            }
        }
    }

    // epilogue: C/D layout col=lane&15, row=4*(lane>>4)+r
    const int crow0 = (lane >> 4) << 2;
#pragma unroll
    for (int i = 0; i < 4; ++i) {
#pragma unroll
        for (int j = 0; j < 4; ++j) {
            int col = colbase + wn * 64 + j * 16 + fr;
            float bb = bias[col];
#pragma unroll
            for (int r = 0; r < 4; ++r) {
                int row = rowbase + wm * 64 + i * 16 + crow0 + r;
                if (row < M)
                    out[(size_t)row * HIDC + col] = f2bf(fmaxf(acc[i][j][r] + bb, 0.0f));
            }
        }
    }
}

// ---------- segment-max pool ----------
__global__ void pool_max(const unsigned short* __restrict__ h, const int* __restrict__ gstart,
                         const int* __restrict__ gend, float* __restrict__ xc, int col_off) {
    int g = blockIdx.x;
    int c = threadIdx.x;
    float m = 0.0f;
    int s = gstart[g], e = gend[g];
    for (int i = s; i < e; ++i) m = fmaxf(m, bf2f(h[(size_t)i * HIDC + c]));
    xc[(size_t)g * (3 * HIDC) + col_off + c] = m;
}

// ---------- head MLPs ----------
__global__ void mlp1(const float* __restrict__ xc, const float* __restrict__ W,
                     const float* __restrict__ b, float* __restrict__ hmid) {
    __shared__ float row[3 * HIDC];
    int g = blockIdx.x;
    for (int i = threadIdx.x; i < 3 * HIDC; i += 256) row[i] = xc[(size_t)g * (3 * HIDC) + i];
    __syncthreads();
    float acc = b[threadIdx.x];
    for (int k = 0; k < 3 * HIDC; ++k) acc += row[k] * W[(size_t)k * HIDC + threadIdx.x];
    hmid[(size_t)g * HIDC + threadIdx.x] = fmaxf(acc, 0.0f);
}

__global__ void mlp2(const float* __restrict__ hmid, const float* __restrict__ W,
                     const float* __restrict__ b, float* __restrict__ out) {
    __shared__ float row[HIDC];
    int g = blockIdx.x;
    for (int i = threadIdx.x; i < HIDC; i += 128) row[i] = hmid[(size_t)g * HIDC + i];
    __syncthreads();
    float acc = b[threadIdx.x];
    for (int k = 0; k < HIDC; ++k) acc += row[k] * W[(size_t)k * OUT_DIMC + threadIdx.x];
    out[(size_t)g * OUT_DIMC + threadIdx.x] = acc;
}

static inline char* align_up(char* p, size_t a) {
    return (char*)(((uintptr_t)p + a - 1) & ~(uintptr_t)(a - 1));
}

extern "C" void kernel_launch(void* const* d_in, const int* in_sizes, int n_in,
                              void* d_out, int out_size, void* d_ws, size_t ws_size,
                              hipStream_t stream) {
    const float* x = (const float*)d_in[0];
    const int* edge_index = (const int*)d_in[1];
    const int* batch = (const int*)d_in[2];
    const float* W1l = (const float*)d_in[3];
    const float* W1r = (const float*)d_in[4];
    const float* b1 = (const float*)d_in[5];
    const float* W2l = (const float*)d_in[6];
    const float* W2r = (const float*)d_in[7];
    const float* b2 = (const float*)d_in[8];
    const float* W3l = (const float*)d_in[9];
    const float* W3r = (const float*)d_in[10];
    const float* b3 = (const float*)d_in[11];
    const float* Wlin1 = (const float*)d_in[12];
    const float* blin1 = (const float*)d_in[13];
    const float* Wlin2 = (const float*)d_in[14];
    const float* blin2 = (const float*)d_in[15];
    float* out = (float*)d_out;

    const int N = N_NODESC, E = N_EDGESC;
    const int* src = edge_index;
    const int* dst = edge_index + E;

    // ---- workspace carve-up ----
    char* w0 = (char*)d_ws;
    char* w = w0;
    int* cnt = (int*)w;        w = align_up(w + (size_t)N * 4, 256);
    float* invc = (float*)w;   w = align_up(w + (size_t)N * 4, 256);
    int* row_ofs = (int*)w;    w = align_up(w + (size_t)(N + 1) * 4, 256);
    int* bsum = (int*)w;       w = align_up(w + (size_t)SCAN_NBLK * 4, 256);
    int* csr = (int*)w;        w = align_up(w + (size_t)E * 4, 256);
    int* gstart = (int*)w;     w = align_up(w + (size_t)N_GRAPHSC * 4, 256);
    int* gend = (int*)w;       w = align_up(w + (size_t)N_GRAPHSC * 4, 256);
    float* xc = (float*)w;     w = align_up(w + (size_t)N_GRAPHSC * 3 * HIDC * 4, 256);
    float* hmid = (float*)w;   w = align_up(w + (size_t)N_GRAPHSC * HIDC * 4, 256);
    unsigned short* W2lT = (unsigned short*)w; w = align_up(w + (size_t)HIDC * HIDC * 2, 256);
    unsigned short* W2rT = (unsigned short*)w; w = align_up(w + (size_t)HIDC * HIDC * 2, 256);
    unsigned short* W3lT = (unsigned short*)w; w = align_up(w + (size_t)HIDC * HIDC * 2, 256);
    unsigned short* W3rT = (unsigned short*)w; w = align_up(w + (size_t)HIDC * HIDC * 2, 256);
    char* aggU = w;            w = align_up(w + (size_t)N * HIDC * 2, 256);
    unsigned short* h1 = (unsigned short*)w;  w = align_up(w + (size_t)N * HIDC * 2, 256);
    unsigned short* h2 = (unsigned short*)w;  w = align_up(w + (size_t)N * HIDC * 2, 256);
    size_t required = (size_t)(w - w0);
    if (ws_size < required) return;

    float* agg25 = (float*)aggU;
    unsigned short* aggH = (unsigned short*)aggU;

    const int nbN = (N + 255) / 256;
    const int nbE = (E + 255) / 256;
    const dim3 gemm_grid_f32((N + 63) / 64, HIDC / 64);
    const dim3 tgrid(16, 16);

    // weight transposes
    wtransT<<<tgrid, 256, 0, stream>>>(W2l, W2lT);
    wtransT<<<tgrid, 256, 0, stream>>>(W2r, W2rT);
    wtransT<<<tgrid, 256, 0, stream>>>(W3l, W3lT);
    wtransT<<<tgrid, 256, 0, stream>>>(W3r, W3rT);

    // degrees + inv
    fill_u32<<<nbN, 256, 0, stream>>>((unsigned*)cnt, 0u, N);
    deg_kernel<<<nbE, 256, 0, stream>>>(dst, cnt, E);
    inv_kernel<<<nbN, 256, 0, stream>>>(cnt, invc, N);
    // CSR offsets: hierarchical scan
    scan_partial<<<SCAN_NBLK, SCAN_BLK, 0, stream>>>(cnt, row_ofs, bsum);
    scan_bsums<<<1, 128, 0, stream>>>(bsum);
    scan_add<<<SCAN_NBLK, SCAN_BLK, 0, stream>>>(row_ofs, bsum);
    fill_u32<<<nbN, 256, 0, stream>>>((unsigned*)cnt, 0u, N);
    csr_fill<<<nbE, 256, 0, stream>>>(src, dst, row_ofs, cnt, csr, E);
    // graph ranges
    fill_u32<<<1, 256, 0, stream>>>((unsigned*)gstart, (unsigned)N, N_GRAPHSC);
    fill_u32<<<1, 256, 0, stream>>>((unsigned*)gend, 0u, N_GRAPHSC);
    ranges_bounds<<<nbN, 256, 0, stream>>>(batch, gstart, gend, N);

    // ---- layer 1 (K=25, f32) ----
    gather25<<<(N * 32 + 255) / 256, 256, 0, stream>>>(x, row_ofs, csr, invc, agg25);
    sage_gemm_f32<IN_DIMC><<<gemm_grid_f32, 256, 0, stream>>>(agg25, x, W1l, W1r, b1, h1, N);
    pool_max<<<N_GRAPHSC, 256, 0, stream>>>(h1, gstart, gend, xc, 0);

    // ---- layer 2 (MFMA, B-in-LDS) ----
    gather256<<<(N * 64 + 255) / 256, 256, 0, stream>>>(h1, row_ofs, csr, invc, aggH);
    sage_gemm_mfma<<<GEMM_GRID, 256, 0, stream>>>(aggH, h1, W2lT, W2rT, b2, h2, N);
    pool_max<<<N_GRAPHSC, 256, 0, stream>>>(h2, gstart, gend, xc, HIDC);

    // ---- layer 3 (MFMA, B-in-LDS) ----
    gather256<<<(N * 64 + 255) / 256, 256, 0, stream>>>(h2, row_ofs, csr, invc, aggH);
    sage_gemm_mfma<<<GEMM_GRID, 256, 0, stream>>>(aggH, h2, W3lT, W3rT, b3, h1, N);
    pool_max<<<N_GRAPHSC, 256, 0, stream>>>(h1, gstart, gend, xc, 2 * HIDC);

    // ---- head ----
    mlp1<<<N_GRAPHSC, 256, 0, stream>>>(xc, Wlin1, blin1, hmid);
    mlp2<<<N_GRAPHSC, 128, 0, stream>>>(hmid, Wlin2, blin2, out);
}